// Round 1
// baseline (7808.727 us; speedup 1.0000x reference)
//
#include <hip/hip_runtime.h>
#include <math.h>

namespace {
constexpr int B = 512, T = 80, F = 32, H = 512, SEQ = 64;
// output row stride = (LA+1)*OUT = 17*2
constexpr int OSTR = 34;

// ---------------- fused LSTM layer kernel ----------------
// For a 32(batch) x 32(h-col) tile:
//   gates = X1 @ W1^T + X2 @ W2^T + b1 + b2   (128 gate cols = 4 strips i,f,g,o)
//   c' = sig(f)*c + sig(i)*tanh(g);  h' = sig(o)*tanh(c')
// K1 = width of X1 (32 for layer0 x_t, 512 for layer1 h0). X2 is always [B,512].
template<int K1>
__global__ __launch_bounds__(256)
void lstm_layer_kernel(const float* __restrict__ x1, int x1s,
                       const float* __restrict__ x2,
                       const float* __restrict__ w1,   // [2048, K1]
                       const float* __restrict__ w2,   // [2048, 512]
                       const float* __restrict__ b1,   // [2048]
                       const float* __restrict__ b2,   // [2048]
                       float* __restrict__ cst,        // [B,512] in/out
                       float* __restrict__ hout,       // [B,512]
                       const float* __restrict__ fb,   // [B,2] feedback (or null)
                       int fbs)
{
  __shared__ float As[32][36];    // [k][m], +4 pad keeps float4 alignment
  __shared__ float Ws[32][132];   // [k][n]
  __shared__ float Gs[32][132];   // gates [m][n]

  const int tid = threadIdx.x;
  const int tn = tid & 31, tm = tid >> 5;       // tn: 0..31 (4 cols each), tm: 0..7 (4 rows each)
  const int row0 = blockIdx.y * 32;             // batch rows
  const int j0   = blockIdx.x * 32;             // h columns

  float acc[4][4] = {};

  constexpr int NT1 = K1 / 32;
  constexpr int NT  = NT1 + 16;
  for (int kt = 0; kt < NT; ++kt) {
    const bool p1 = (kt < NT1);
    const float* X = p1 ? x1 : x2;
    const int xs = p1 ? x1s : H;
    const int kbase = p1 ? kt * 32 : (kt - NT1) * 32;
    // ---- A tile: 32 rows x 32 k (coalesced along k) ----
    #pragma unroll
    for (int i = 0; i < 4; ++i) {
      int lin = tid + i * 256;
      int m = lin >> 5, k = lin & 31;
      float v = X[(size_t)(row0 + m) * xs + kbase + k];
      if (K1 == 32) {
        if (fb != nullptr && p1) {
          int kc = kbase + k;
          if (kc == 4 || kc == 5) v = fb[(row0 + m) * fbs + (kc - 4)];
        }
      }
      As[k][m] = v;
    }
    // ---- W tile: 128 gate rows x 32 k (coalesced along k) ----
    const float* W = p1 ? w1 : w2;
    const int wk = p1 ? K1 : 512;
    #pragma unroll
    for (int i = 0; i < 16; ++i) {
      int lin = tid + i * 256;
      int n = lin >> 5, k = lin & 31;
      int gn = ((n >> 5) << 9) + j0 + (n & 31);   // strip*512 + j0 + r
      Ws[k][n] = W[(size_t)gn * wk + kbase + k];
    }
    __syncthreads();
    #pragma unroll
    for (int k = 0; k < 32; ++k) {
      float4 av = *(const float4*)&As[k][tm * 4];
      float4 wv = *(const float4*)&Ws[k][tn * 4];
      float a[4] = {av.x, av.y, av.z, av.w};
      float w[4] = {wv.x, wv.y, wv.z, wv.w};
      #pragma unroll
      for (int mm = 0; mm < 4; ++mm)
        #pragma unroll
        for (int nn = 0; nn < 4; ++nn)
          acc[mm][nn] += a[mm] * w[nn];
    }
    __syncthreads();
  }

  // ---- bias + stash gates to LDS ----
  #pragma unroll
  for (int mm = 0; mm < 4; ++mm) {
    #pragma unroll
    for (int nn = 0; nn < 4; ++nn) {
      int nl = tn * 4 + nn;
      int gn = ((nl >> 5) << 9) + j0 + (nl & 31);
      Gs[tm * 4 + mm][nl] = acc[mm][nn] + b1[gn] + b2[gn];
    }
  }
  __syncthreads();

  // ---- cell update: 32x32 h elements, 4 per thread ----
  #pragma unroll
  for (int p = 0; p < 4; ++p) {
    int idx = tid + p * 256;
    int m = idx >> 5, j = idx & 31;
    float gi = Gs[m][j];
    float gf = Gs[m][32 + j];
    float gg = Gs[m][64 + j];
    float go = Gs[m][96 + j];
    size_t gidx = (size_t)(row0 + m) * H + j0 + j;
    float c = cst[gidx];
    float si = 1.f / (1.f + expf(-gi));
    float sf = 1.f / (1.f + expf(-gf));
    float so = 1.f / (1.f + expf(-go));
    float c2 = sf * c + si * tanhf(gg);
    cst[gidx] = c2;
    hout[gidx] = so * tanhf(c2);
  }
}

// ---------------- head GEMM: Y = gelu(A @ W^T + b) ----------------
// A [512,512], W [512,512], per-block 32 rows x 128 cols.
__global__ __launch_bounds__(256)
void head_gemm_kernel(const float* __restrict__ A,
                      const float* __restrict__ W,
                      const float* __restrict__ bias,
                      float* __restrict__ Y)
{
  __shared__ float As[32][36];
  __shared__ float Ws[32][132];
  const int tid = threadIdx.x;
  const int tn = tid & 31, tm = tid >> 5;
  const int row0 = blockIdx.y * 32;
  const int n0 = blockIdx.x * 128;
  float acc[4][4] = {};
  for (int kt = 0; kt < 16; ++kt) {
    #pragma unroll
    for (int i = 0; i < 4; ++i) {
      int lin = tid + i * 256;
      int m = lin >> 5, k = lin & 31;
      As[k][m] = A[(size_t)(row0 + m) * 512 + kt * 32 + k];
    }
    #pragma unroll
    for (int i = 0; i < 16; ++i) {
      int lin = tid + i * 256;
      int n = lin >> 5, k = lin & 31;
      Ws[k][n] = W[(size_t)(n0 + n) * 512 + kt * 32 + k];
    }
    __syncthreads();
    #pragma unroll
    for (int k = 0; k < 32; ++k) {
      float4 av = *(const float4*)&As[k][tm * 4];
      float4 wv = *(const float4*)&Ws[k][tn * 4];
      float a[4] = {av.x, av.y, av.z, av.w};
      float w[4] = {wv.x, wv.y, wv.z, wv.w};
      #pragma unroll
      for (int mm = 0; mm < 4; ++mm)
        #pragma unroll
        for (int nn = 0; nn < 4; ++nn)
          acc[mm][nn] += a[mm] * w[nn];
    }
    __syncthreads();
  }
  #pragma unroll
  for (int mm = 0; mm < 4; ++mm) {
    float o[4];
    #pragma unroll
    for (int nn = 0; nn < 4; ++nn) {
      float v = acc[mm][nn] + bias[n0 + tn * 4 + nn];
      o[nn] = 0.5f * v * (1.f + erff(v * 0.70710678118654752f));
    }
    *(float4*)&Y[(size_t)(row0 + tm * 4 + mm) * 512 + n0 + tn * 4] =
        make_float4(o[0], o[1], o[2], o[3]);
  }
}

// ---------------- fc3: out[b, o] = y2[b,:] . w[o,:] + b[o] ----------------
__global__ __launch_bounds__(256)
void fc3_kernel(const float* __restrict__ Yin,
                const float* __restrict__ W,    // [2,512]
                const float* __restrict__ bias, // [2]
                float* __restrict__ outp)       // d_out + kidx*2, row stride 34
{
  int g = blockIdx.x * 256 + threadIdx.x;  // 0..1023
  int b = g >> 1, o = g & 1;
  const float* yr = Yin + (size_t)b * 512;
  const float* wr = W + (size_t)o * 512;
  float s = bias[o];
  for (int k = 0; k < 512; ++k) s += yr[k] * wr[k];
  outp[b * OSTR + o] = s;
}

} // namespace

extern "C" void kernel_launch(void* const* d_in, const int* in_sizes, int n_in,
                              void* d_out, int out_size, void* d_ws, size_t ws_size,
                              hipStream_t stream)
{
  const float* x     = (const float*)d_in[0];
  const float* w_ih0 = (const float*)d_in[1];
  const float* w_hh0 = (const float*)d_in[2];
  const float* b_ih0 = (const float*)d_in[3];
  const float* b_hh0 = (const float*)d_in[4];
  const float* w_ih1 = (const float*)d_in[5];
  const float* w_hh1 = (const float*)d_in[6];
  const float* b_ih1 = (const float*)d_in[7];
  const float* b_hh1 = (const float*)d_in[8];
  const float* fc1_w = (const float*)d_in[9];
  const float* fc1_b = (const float*)d_in[10];
  const float* fc2_w = (const float*)d_in[11];
  const float* fc2_b = (const float*)d_in[12];
  const float* fc3_w = (const float*)d_in[13];
  const float* fc3_b = (const float*)d_in[14];
  float* out = (float*)d_out;
  float* ws = (float*)d_ws;

  const size_t SB = (size_t)B * H;  // 512*512 floats (1 MB)
  float* h0a = ws;            // zeroed (contiguous first 4 buffers)
  float* h1a = ws + SB;       // zeroed
  float* c0  = ws + 2 * SB;   // zeroed
  float* c1  = ws + 3 * SB;   // zeroed
  float* h0b = ws + 4 * SB;
  float* h1b = ws + 5 * SB;
  float* y1  = ws + 6 * SB;
  float* y2  = ws + 7 * SB;

  hipMemsetAsync(ws, 0, 4 * SB * sizeof(float), stream);

  dim3 blk(256);
  dim3 gridL(16, 16);  // 512/32 cols x 512/32 rows
  dim3 gridH(4, 16);   // 512/128 cols x 512/32 rows

  float* h0p = h0a; float* h0n = h0b;
  float* h1p = h1a; float* h1n = h1b;

  for (int t = 0; t < T; ++t) {
    const float* fb = (t >= SEQ) ? out + (size_t)(t - SEQ) * 2 : nullptr;
    lstm_layer_kernel<32><<<gridL, blk, 0, stream>>>(
        x + (size_t)t * F, T * F, h0p, w_ih0, w_hh0, b_ih0, b_hh0,
        c0, h0n, fb, OSTR);
    lstm_layer_kernel<512><<<gridL, blk, 0, stream>>>(
        h0n, H, h1p, w_ih1, w_hh1, b_ih1, b_hh1,
        c1, h1n, nullptr, 0);
    if (t >= SEQ - 1) {
      int kidx = t - (SEQ - 1);   // 0..16
      head_gemm_kernel<<<gridH, blk, 0, stream>>>(h1n, fc1_w, fc1_b, y1);
      head_gemm_kernel<<<gridH, blk, 0, stream>>>(y1, fc2_w, fc2_b, y2);
      fc3_kernel<<<dim3(4), blk, 0, stream>>>(y2, fc3_w, fc3_b, out + (size_t)kidx * 2);
    }
    float* tmp = h0p; h0p = h0n; h0n = tmp;
    tmp = h1p; h1p = h1n; h1n = tmp;
  }
}

// Round 2
// 4260.028 us; speedup vs baseline: 1.8330x; 1.8330x over previous
//
#include <hip/hip_runtime.h>
#include <math.h>

typedef short s16x8 __attribute__((ext_vector_type(8)));
typedef float f32x4 __attribute__((ext_vector_type(4)));

namespace {
constexpr int T = 80, Fdim = 32, H = 512, SEQ = 64, OSTR = 34;
constexpr size_t SB = 512 * 512;  // elements in one [B,H] buffer

__device__ __forceinline__ unsigned short f2bf(float f) {
  union { float f; unsigned u; } x; x.f = f;
  unsigned u = x.u; u += 0x7fffu + ((u >> 16) & 1u);
  return (unsigned short)(u >> 16);
}
__device__ __forceinline__ float bf2f(unsigned short s) {
  union { unsigned u; float f; } x; x.u = ((unsigned)s) << 16; return x.f;
}

// ---------------- weight pre-pack ----------------
// dst layout: [kc][jb] blocks of 8KB: [strip(4)][half(2)][lane(64)][8 bf16]
// lane l holds W[n][k], k = kc*32 + (l>>4)*8 + i
// layer: n = strip*512 + jb*16 + (l&15);  head: n = jb*64 + strip*16 + (l&15)
__global__ __launch_bounds__(256)
void pack_w_kernel(const float* __restrict__ w1, const float* __restrict__ w2,
                   int K1, int K2, int JB, int head, unsigned short* __restrict__ dst) {
  int bid = blockIdx.x;
  int kc = bid / JB, jb = bid % JB;
  int tid = threadIdx.x;
  int strip = tid >> 6, l = tid & 63;
  int nl = l & 15, kg = l >> 4;
  int n = head ? (jb * 64 + strip * 16 + nl) : (strip * 512 + jb * 16 + nl);
  s16x8 h8, l8;
  #pragma unroll
  for (int i = 0; i < 8; ++i) {
    int k = kc * 32 + kg * 8 + i;
    float v = (k < K1) ? w1[(size_t)n * K1 + k] : w2[(size_t)n * K2 + (k - K1)];
    unsigned short h = f2bf(v);
    h8[i] = (short)h;
    l8[i] = (short)f2bf(v - bf2f(h));
  }
  size_t base = (size_t)bid * 4096;
  *(s16x8*)&dst[base + (size_t)(strip * 2 + 0) * 512 + l * 8] = h8;
  *(s16x8*)&dst[base + (size_t)(strip * 2 + 1) * 512 + l * 8] = l8;
}

__global__ __launch_bounds__(256)
void bsum_kernel(const float* bi0, const float* bh0, const float* bi1, const float* bh1,
                 float* bs0, float* bs1) {
  int i = blockIdx.x * 256 + threadIdx.x;
  if (i < 2048) bs0[i] = bi0[i] + bh0[i];
  else { int j = i - 2048; bs1[j] = bi1[j] + bh1[j]; }
}

// ---------------- fused LSTM layer (split-bf16 MFMA) ----------------
// block: 64 batch rows x 16 h-cols x 4 gate strips; wave w = strip w
// wave tile 64x16 = 4 m-frags of 16x16, acc f32x4[4]
template<int NC, int NC1>
__global__ __launch_bounds__(256)
void lstm_mfma_kernel(const float* __restrict__ a1, int a1s,
                      const float* __restrict__ a2,
                      const unsigned short* __restrict__ Wp,
                      const float* __restrict__ bsum,
                      float* __restrict__ cst,
                      float* __restrict__ hout,
                      const float* __restrict__ fb) {
  __shared__ unsigned short Ash[2][4096];  // [buf][mf(4)][half(2)][lane(64)][8]
  __shared__ unsigned short Bsh[2][4096];  // [buf][strip(4)][half(2)][lane(64)][8]
  __shared__ float Gs[4][64][16];

  const int tid = threadIdx.x;
  const int w = tid >> 6, l = tid & 63;
  const int jb = blockIdx.x;          // 0..31
  const int row0 = blockIdx.y * 64;
  const int j0 = jb * 16;

  f32x4 acc[4];
  #pragma unroll
  for (int mf = 0; mf < 4; ++mf) acc[mf] = {0.f, 0.f, 0.f, 0.f};

  const int srow = tid >> 2, skg = tid & 3;
  const int slane = skg * 16 + (srow & 15), smf = srow >> 4;

  auto stage = [&](int kc, int buf) {
    // B: fragment-linear 8KB chunk, fully coalesced
    size_t gbase = (size_t)(kc * 32 + jb) * 4096;
    s16x8 b0 = *(const s16x8*)&Wp[gbase + (w * 2 + 0) * 512 + l * 8];
    s16x8 b1 = *(const s16x8*)&Wp[gbase + (w * 2 + 1) * 512 + l * 8];
    *(s16x8*)&Bsh[buf][(w * 2 + 0) * 512 + l * 8] = b0;
    *(s16x8*)&Bsh[buf][(w * 2 + 1) * 512 + l * 8] = b1;
    // A: fp32 -> bf16 hi/lo, fragment-linear
    const float* src; int ss; int kb;
    if (kc < NC1) { src = a1; ss = a1s; kb = kc * 32; }
    else          { src = a2; ss = H;   kb = (kc - NC1) * 32; }
    const float* p = src + (size_t)(row0 + srow) * ss + kb + skg * 8;
    float4 v0 = *(const float4*)p;
    float4 v1 = *(const float4*)(p + 4);
    float v[8] = {v0.x, v0.y, v0.z, v0.w, v1.x, v1.y, v1.z, v1.w};
    if (NC1 == 1 && fb != nullptr && kc == 0) {
      #pragma unroll
      for (int i = 0; i < 8; ++i) {
        int kcol = skg * 8 + i;
        if (kcol == 4 || kcol == 5) v[i] = fb[(row0 + srow) * OSTR + (kcol - 4)];
      }
    }
    s16x8 h8, l8;
    #pragma unroll
    for (int i = 0; i < 8; ++i) {
      unsigned short h = f2bf(v[i]);
      h8[i] = (short)h;
      l8[i] = (short)f2bf(v[i] - bf2f(h));
    }
    *(s16x8*)&Ash[buf][(smf * 2 + 0) * 512 + slane * 8] = h8;
    *(s16x8*)&Ash[buf][(smf * 2 + 1) * 512 + slane * 8] = l8;
  };

  stage(0, 0);
  __syncthreads();
  for (int kc = 0; kc < NC; ++kc) {
    int buf = kc & 1;
    if (kc + 1 < NC) stage(kc + 1, buf ^ 1);
    s16x8 Bhi = *(const s16x8*)&Bsh[buf][(w * 2 + 0) * 512 + l * 8];
    s16x8 Blo = *(const s16x8*)&Bsh[buf][(w * 2 + 1) * 512 + l * 8];
    #pragma unroll
    for (int mf = 0; mf < 4; ++mf) {
      s16x8 Ahi = *(const s16x8*)&Ash[buf][(mf * 2 + 0) * 512 + l * 8];
      s16x8 Alo = *(const s16x8*)&Ash[buf][(mf * 2 + 1) * 512 + l * 8];
      acc[mf] = __builtin_amdgcn_mfma_f32_16x16x32_bf16(Ahi, Bhi, acc[mf], 0, 0, 0);
      acc[mf] = __builtin_amdgcn_mfma_f32_16x16x32_bf16(Ahi, Blo, acc[mf], 0, 0, 0);
      acc[mf] = __builtin_amdgcn_mfma_f32_16x16x32_bf16(Alo, Bhi, acc[mf], 0, 0, 0);
    }
    __syncthreads();
  }

  // bias + gate stash
  float bs = bsum[w * 512 + j0 + (l & 15)];
  #pragma unroll
  for (int mf = 0; mf < 4; ++mf)
    #pragma unroll
    for (int r = 0; r < 4; ++r)
      Gs[w][mf * 16 + (l >> 4) * 4 + r][l & 15] = acc[mf][r] + bs;
  __syncthreads();

  // cell update
  #pragma unroll
  for (int p2 = 0; p2 < 4; ++p2) {
    int idx = tid + p2 * 256;
    int row = idx >> 4, col = idx & 15;
    float gi = Gs[0][row][col], gf = Gs[1][row][col];
    float gg = Gs[2][row][col], go = Gs[3][row][col];
    size_t gx = (size_t)(row0 + row) * H + j0 + col;
    float si = 1.f / (1.f + expf(-gi));
    float sf = 1.f / (1.f + expf(-gf));
    float so = 1.f / (1.f + expf(-go));
    float c2 = sf * cst[gx] + si * tanhf(gg);
    cst[gx] = c2;
    hout[gx] = so * tanhf(c2);
  }
}

// ---------------- head GEMM: Y = gelu(A @ W^T + b) ----------------
// 64x64 tile, 4 waves 2x2, wave tile 32x32 (2x2 frags)
__global__ __launch_bounds__(256)
void head_mfma_kernel(const float* __restrict__ A,
                      const unsigned short* __restrict__ Wp,
                      const float* __restrict__ bias,
                      float* __restrict__ Y) {
  __shared__ unsigned short Ash[2][4096];
  __shared__ unsigned short Bsh[2][4096];
  const int tid = threadIdx.x;
  const int w = tid >> 6, l = tid & 63;
  const int wm = w >> 1, wn = w & 1;
  const int jbb = blockIdx.x;          // 0..7
  const int row0 = blockIdx.y * 64;
  const int j0 = jbb * 64;
  f32x4 acc[2][2];
  #pragma unroll
  for (int a = 0; a < 2; ++a)
    #pragma unroll
    for (int b = 0; b < 2; ++b) acc[a][b] = {0.f, 0.f, 0.f, 0.f};

  const int srow = tid >> 2, skg = tid & 3;
  const int slane = skg * 16 + (srow & 15), smf = srow >> 4;

  auto stage = [&](int kc, int buf) {
    size_t gbase = (size_t)(kc * 8 + jbb) * 4096;
    s16x8 b0 = *(const s16x8*)&Wp[gbase + (w * 2 + 0) * 512 + l * 8];
    s16x8 b1 = *(const s16x8*)&Wp[gbase + (w * 2 + 1) * 512 + l * 8];
    *(s16x8*)&Bsh[buf][(w * 2 + 0) * 512 + l * 8] = b0;
    *(s16x8*)&Bsh[buf][(w * 2 + 1) * 512 + l * 8] = b1;
    const float* p = A + (size_t)(row0 + srow) * H + kc * 32 + skg * 8;
    float4 v0 = *(const float4*)p;
    float4 v1 = *(const float4*)(p + 4);
    float v[8] = {v0.x, v0.y, v0.z, v0.w, v1.x, v1.y, v1.z, v1.w};
    s16x8 h8, l8;
    #pragma unroll
    for (int i = 0; i < 8; ++i) {
      unsigned short h = f2bf(v[i]);
      h8[i] = (short)h;
      l8[i] = (short)f2bf(v[i] - bf2f(h));
    }
    *(s16x8*)&Ash[buf][(smf * 2 + 0) * 512 + slane * 8] = h8;
    *(s16x8*)&Ash[buf][(smf * 2 + 1) * 512 + slane * 8] = l8;
  };

  stage(0, 0);
  __syncthreads();
  for (int kc = 0; kc < 16; ++kc) {
    int buf = kc & 1;
    if (kc + 1 < 16) stage(kc + 1, buf ^ 1);
    #pragma unroll
    for (int nf = 0; nf < 2; ++nf) {
      s16x8 Bhi = *(const s16x8*)&Bsh[buf][((wn * 2 + nf) * 2 + 0) * 512 + l * 8];
      s16x8 Blo = *(const s16x8*)&Bsh[buf][((wn * 2 + nf) * 2 + 1) * 512 + l * 8];
      #pragma unroll
      for (int mf = 0; mf < 2; ++mf) {
        s16x8 Ahi = *(const s16x8*)&Ash[buf][((wm * 2 + mf) * 2 + 0) * 512 + l * 8];
        s16x8 Alo = *(const s16x8*)&Ash[buf][((wm * 2 + mf) * 2 + 1) * 512 + l * 8];
        acc[mf][nf] = __builtin_amdgcn_mfma_f32_16x16x32_bf16(Ahi, Bhi, acc[mf][nf], 0, 0, 0);
        acc[mf][nf] = __builtin_amdgcn_mfma_f32_16x16x32_bf16(Ahi, Blo, acc[mf][nf], 0, 0, 0);
        acc[mf][nf] = __builtin_amdgcn_mfma_f32_16x16x32_bf16(Alo, Bhi, acc[mf][nf], 0, 0, 0);
      }
    }
    __syncthreads();
  }
  #pragma unroll
  for (int mf = 0; mf < 2; ++mf)
    #pragma unroll
    for (int nf = 0; nf < 2; ++nf) {
      int col = j0 + (wn * 2 + nf) * 16 + (l & 15);
      float bv = bias[col];
      #pragma unroll
      for (int r = 0; r < 4; ++r) {
        int row = row0 + (wm * 2 + mf) * 16 + (l >> 4) * 4 + r;
        float vv = acc[mf][nf][r] + bv;
        Y[(size_t)row * H + col] = 0.5f * vv * (1.f + erff(vv * 0.70710678118654752f));
      }
    }
}

// ---------------- fc3: one wave per output ----------------
__global__ __launch_bounds__(256)
void fc3_kernel(const float* __restrict__ Yin, const float* __restrict__ Wf,
                const float* __restrict__ bf, float* __restrict__ outp) {
  int w = threadIdx.x >> 6, l = threadIdx.x & 63;
  int idx = blockIdx.x * 4 + w;
  int b = idx >> 1, o = idx & 1;
  const float* yr = Yin + (size_t)b * H + l * 8;
  const float* wr = Wf + (size_t)o * H + l * 8;
  float s = 0.f;
  #pragma unroll
  for (int i = 0; i < 8; ++i) s += yr[i] * wr[i];
  #pragma unroll
  for (int d = 32; d > 0; d >>= 1) s += __shfl_down(s, d, 64);
  if (l == 0) outp[b * OSTR + o] = s + bf[o];
}

} // namespace

extern "C" void kernel_launch(void* const* d_in, const int* in_sizes, int n_in,
                              void* d_out, int out_size, void* d_ws, size_t ws_size,
                              hipStream_t stream) {
  const float* x     = (const float*)d_in[0];
  const float* w_ih0 = (const float*)d_in[1];
  const float* w_hh0 = (const float*)d_in[2];
  const float* b_ih0 = (const float*)d_in[3];
  const float* b_hh0 = (const float*)d_in[4];
  const float* w_ih1 = (const float*)d_in[5];
  const float* w_hh1 = (const float*)d_in[6];
  const float* b_ih1 = (const float*)d_in[7];
  const float* b_hh1 = (const float*)d_in[8];
  const float* fc1_w = (const float*)d_in[9];
  const float* fc1_b = (const float*)d_in[10];
  const float* fc2_w = (const float*)d_in[11];
  const float* fc2_b = (const float*)d_in[12];
  const float* fc3_w = (const float*)d_in[13];
  const float* fc3_b = (const float*)d_in[14];
  float* out = (float*)d_out;
  char* wsb = (char*)d_ws;

  // workspace layout (bytes)
  constexpr size_t O_WP0  = 0;                         // 17*32*8192 = 4456448
  constexpr size_t O_WP1  = 4456448;                   // 32*32*8192 = 8388608
  constexpr size_t O_WPF1 = O_WP1 + 8388608;           // 16*8*8192  = 1048576
  constexpr size_t O_WPF2 = O_WPF1 + 1048576;
  constexpr size_t O_BS0  = O_WPF2 + 1048576;          // 8192
  constexpr size_t O_BS1  = O_BS0 + 8192;
  constexpr size_t O_ACT  = O_BS1 + 8192;

  unsigned short* Wp0  = (unsigned short*)(wsb + O_WP0);
  unsigned short* Wp1  = (unsigned short*)(wsb + O_WP1);
  unsigned short* Wpf1 = (unsigned short*)(wsb + O_WPF1);
  unsigned short* Wpf2 = (unsigned short*)(wsb + O_WPF2);
  float* bs0 = (float*)(wsb + O_BS0);
  float* bs1 = (float*)(wsb + O_BS1);
  float* acts = (float*)(wsb + O_ACT);

  float* h0a = acts;
  float* h1a = acts + SB;
  float* c0  = acts + 2 * SB;
  float* c1  = acts + 3 * SB;
  float* h0b = acts + 4 * SB;
  float* h1b = acts + 5 * SB;
  float* y1  = acts + 6 * SB;
  float* y2  = acts + 7 * SB;

  // pre-pack weights + biases; zero initial state
  pack_w_kernel<<<dim3(17 * 32), 256, 0, stream>>>(w_ih0, w_hh0, 32, 512, 32, 0, Wp0);
  pack_w_kernel<<<dim3(32 * 32), 256, 0, stream>>>(w_ih1, w_hh1, 512, 512, 32, 0, Wp1);
  pack_w_kernel<<<dim3(16 * 8), 256, 0, stream>>>(fc1_w, fc1_w, 512, 512, 8, 1, Wpf1);
  pack_w_kernel<<<dim3(16 * 8), 256, 0, stream>>>(fc2_w, fc2_w, 512, 512, 8, 1, Wpf2);
  bsum_kernel<<<dim3(16), 256, 0, stream>>>(b_ih0, b_hh0, b_ih1, b_hh1, bs0, bs1);
  hipMemsetAsync(acts, 0, 4 * SB * sizeof(float), stream);

  dim3 blk(256);
  dim3 gridL(32, 8);   // 32 j-blocks x 8 m-blocks
  dim3 gridH(8, 8);    // 8 col-blocks x 8 m-blocks

  float* h0p = h0a; float* h0n = h0b;
  float* h1p = h1a; float* h1n = h1b;

  for (int t = 0; t < T; ++t) {
    const float* fb = (t >= SEQ) ? out + (size_t)(t - SEQ) * 2 : nullptr;
    lstm_mfma_kernel<17, 1><<<gridL, blk, 0, stream>>>(
        x + (size_t)t * Fdim, T * Fdim, h0p, Wp0, bs0, c0, h0n, fb);
    lstm_mfma_kernel<32, 16><<<gridL, blk, 0, stream>>>(
        h0n, H, h1p, Wp1, bs1, c1, h1n, nullptr);
    if (t >= SEQ - 1) {
      int kidx = t - (SEQ - 1);
      head_mfma_kernel<<<gridH, blk, 0, stream>>>(h1n, Wpf1, fc1_b, y1);
      head_mfma_kernel<<<gridH, blk, 0, stream>>>(y1, Wpf2, fc2_b, y2);
      fc3_kernel<<<dim3(256), blk, 0, stream>>>(y2, fc3_w, fc3_b, out + (size_t)kidx * 2);
    }
    float* tmp = h0p; h0p = h0n; h0n = tmp;
    tmp = h1p; h1p = h1n; h1n = tmp;
  }
}